// Round 15
// baseline (793.231 us; speedup 1.0000x reference)
//
#include <hip/hip_runtime.h>
#include <stdint.h>

typedef __attribute__((ext_vector_type(4))) int iv4;      // 4 VGPRs (16B)
typedef __attribute__((ext_vector_type(16))) char i8x16;

#define BM 256
#define BN 256
#define BKT 64   // K bytes per tile; one 16-KB A + 16-KB B per buffer

// ---- activation quantization: one block per row, per-row scale ----
__global__ __launch_bounds__(256) void quant_act(const float* __restrict__ in,
                                                 signed char* __restrict__ out,
                                                 float* __restrict__ s_a,
                                                 int K) {
  const int row = blockIdx.x;
  const int t = threadIdx.x;
  const float* a = in + (long)row * K;
  float4 v[4];
#pragma unroll
  for (int i = 0; i < 4; ++i)
    v[i] = reinterpret_cast<const float4*>(a)[t * 4 + i];
  float m = 0.f;
#pragma unroll
  for (int i = 0; i < 4; ++i) {
    m = fmaxf(m, fmaxf(fmaxf(fabsf(v[i].x), fabsf(v[i].y)),
                       fmaxf(fabsf(v[i].z), fabsf(v[i].w))));
  }
#pragma unroll
  for (int off = 32; off; off >>= 1) m = fmaxf(m, __shfl_xor(m, off));
  __shared__ float wmax[4];
  const int lane = t & 63, wvq = t >> 6;
  if (lane == 0) wmax[wvq] = m;
  __syncthreads();
  m = fmaxf(fmaxf(wmax[0], wmax[1]), fmaxf(wmax[2], wmax[3]));
  const float inv = m > 0.f ? 127.f / m : 0.f;
  if (t == 0) s_a[row] = m > 0.f ? m / 127.f : 0.f;
  i8x16 q;
#pragma unroll
  for (int i = 0; i < 4; ++i) {
    q[i * 4 + 0] = (char)(int)rintf(fminf(fmaxf(v[i].x * inv, -127.f), 127.f));
    q[i * 4 + 1] = (char)(int)rintf(fminf(fmaxf(v[i].y * inv, -127.f), 127.f));
    q[i * 4 + 2] = (char)(int)rintf(fminf(fmaxf(v[i].z * inv, -127.f), 127.f));
    q[i * 4 + 3] = (char)(int)rintf(fminf(fmaxf(v[i].w * inv, -127.f), 127.f));
  }
  reinterpret_cast<i8x16*>(out + (long)row * K)[t] = q;
}

// ---- weight pack: int32 (|v|<=127) -> int8 ----
__global__ void pack_w(const int* __restrict__ in, signed char* __restrict__ out,
                       long n16) {
  long stride = (long)gridDim.x * blockDim.x;
  for (long i = (long)blockIdx.x * blockDim.x + threadIdx.x; i < n16; i += stride) {
    i8x16 q;
#pragma unroll
    for (int c = 0; c < 4; ++c) {
      int4 w = reinterpret_cast<const int4*>(in)[i * 4 + c];
      q[c * 4 + 0] = (char)w.x;
      q[c * 4 + 1] = (char)w.y;
      q[c * 4 + 2] = (char)w.z;
      q[c * 4 + 3] = (char)w.w;
    }
    reinterpret_cast<i8x16*>(out)[i] = q;
  }
}

#define GLDS16(g, l)                                                          \
  __builtin_amdgcn_global_load_lds(                                           \
      (const __attribute__((address_space(1))) unsigned int*)(g),             \
      (__attribute__((address_space(3))) unsigned int*)(l), 16, 0, 0)

// Inline-asm ds_read_b128 (opaque to SIInsertWaitcnts; no clobbers in-loop
// so no hidden vmcnt(0) drains). rule #18: manual waits + sched_barrier(0).
typedef __attribute__((address_space(3))) const signed char lds_c8;

template <int OFF>
__device__ __forceinline__ iv4 ldsb128(lds_c8* p) {
  iv4 r;
  asm volatile("ds_read_b128 %0, %1 offset:%2" : "=v"(r) : "v"(p), "i"(OFF));
  return r;
}

#define BAR __builtin_amdgcn_s_barrier()
#define SCHEDB __builtin_amdgcn_sched_barrier(0)
#define LGKM_0 asm volatile("s_waitcnt lgkmcnt(0)")
#define VMC_4 asm volatile("s_waitcnt vmcnt(4)")

// 8 MFMAs: acc[I0..I0+3][J0..J0+1] += A4[i] x B2[j] (i8, K=64 per MFMA)
#define MFMA8I(A4, B2, I0, J0)                                                \
  _Pragma("unroll") for (int i = 0; i < 4; ++i)                               \
    _Pragma("unroll") for (int j = 0; j < 2; ++j)                             \
      acc[(I0) + i][(J0) + j] = __builtin_amdgcn_mfma_i32_16x16x64_i8(        \
          A4[i], (B2)[j], acc[(I0) + i][(J0) + j], 0, 0, 0)

// 256x256 int8 GEMM; R14 skeleton (quad-buffer, never-drain vmcnt(4) DMA
// stream, T2 swizzle) + the R10xR12 combination neither tested alone:
// (a) fragment operands are ONE TILE OLD (no lgkm wait precedes any MFMA
//     cluster - the LGKM_0 at tile top is ~free), AND
// (b) the 12 prefetch ds_reads issue in 3 bursts of 4 BETWEEN the four
//     8-MFMA clusters, so the per-wave LDS queue never fills and in-order
//     issue never stalls the wave short of its MFMAs.
// R10 (12-read burst, no waits) and R12 (fine bursts, with waits) were each
// null in bf16; this is the remaining cell of that 2x2.
__global__ __launch_bounds__(512, 2) void gemm256_i8x(
    const signed char* __restrict__ A,   // [M][K] i8 (row-quantized)
    const signed char* __restrict__ W,   // [N][K] i8
    const float* __restrict__ s_a,       // [M] activation row scales
    const float* __restrict__ scale,     // [N] weight col scales
    const float* __restrict__ bias,      // [N]
    float* __restrict__ C,               // [M][N] f32
    int M, int N, int K) {
  __shared__ __align__(16) signed char As[4][256 * 64];  // 64 KiB
  __shared__ __align__(16) signed char Bs[4][256 * 64];  // 64 KiB

  const int tid = threadIdx.x;
  const int lane = tid & 63;
  const int wv = tid >> 6;       // 0..7
  const int wm = wv >> 2;        // 0..1  (wave row: 128 rows)
  const int wn = wv & 3;         // 0..3  (wave col: 64 cols)

  const int nwg = gridDim.x;
  const int bid = blockIdx.x;
  const int wg = ((nwg & 7) == 0) ? ((bid & 7) * (nwg >> 3) + (bid >> 3)) : bid;
  const int mT = M / BM;
  const int bm = wg % mT;        // M-fast: neighbors share W panel
  const int bn = wg / mT;

  const long aRow0 = (long)bm * BM;
  const long wRow0 = (long)bn * BN;

  // staging: chunk c = 16 rows x 64B; lane l -> linear dest slot, inverse-
  // swizzled source column in BYTES (logical 16B-slot (l&3)^((l>>3)&3)).
  const int c0 = wv, c1 = 8 + wv;
  const int sr0 = 16 * c0 + (lane >> 2);
  const int sr1 = 16 * c1 + (lane >> 2);
  const int scB = (((lane & 3) ^ ((lane >> 3) & 3))) * 16;
  const signed char* aS0 = A + (aRow0 + sr0) * (long)K + scB;
  const signed char* aS1 = A + (aRow0 + sr1) * (long)K + scB;
  const signed char* wS0 = W + (wRow0 + sr0) * (long)K + scB;
  const signed char* wS1 = W + (wRow0 + sr1) * (long)K + scB;
  const int d0 = c0 * 1024 + lane * 16;   // byte offset in a buffer
  const int d1 = c1 * 1024 + lane * 16;

  // ds_read bases (bytes): row*64 + swizzled 16B-slot*16 (XOR lane-constant)
  const int sx = (lane >> 4) ^ ((lane >> 1) & 3);
  const int rdA = (wm * 128 + (lane & 15)) * 64 + sx * 16;
  const int rdB = (wn * 64 + (lane & 15)) * 64 + sx * 16;

  iv4 acc[8][4] = {};
  iv4 bA[4], a0A[4], a1A[4];   // fragment set A
  iv4 bB[4], a0B[4], a1B[4];   // fragment set B

  const int nk = K / BKT;   // 64 (guarded % 4 == 0)

  // prologue: stage t0->buf0, t1->buf1; retire t0; stage t2; read t0 -> set A
  GLDS16(aS0, &As[0][d0]);
  GLDS16(aS1, &As[0][d1]);
  GLDS16(wS0, &Bs[0][d0]);
  GLDS16(wS1, &Bs[0][d1]);
  GLDS16(aS0 + BKT, &As[1][d0]);
  GLDS16(aS1 + BKT, &As[1][d1]);
  GLDS16(wS0 + BKT, &Bs[1][d0]);
  GLDS16(wS1 + BKT, &Bs[1][d1]);
  VMC_4;   // t0 retired (t1 in flight)
  BAR;     // t0 published
  GLDS16(aS0 + 2 * BKT, &As[2][d0]);
  GLDS16(aS1 + 2 * BKT, &As[2][d1]);
  GLDS16(wS0 + 2 * BKT, &Bs[2][d0]);
  GLDS16(wS1 + 2 * BKT, &Bs[2][d1]);
  SCHEDB;
  {
    lds_c8* pB = (lds_c8*)&Bs[0][rdB];
    lds_c8* pA = (lds_c8*)&As[0][rdA];
    bA[0] = ldsb128<0>(pB);    bA[1] = ldsb128<1024>(pB);
    bA[2] = ldsb128<2048>(pB); bA[3] = ldsb128<3072>(pB);
    a0A[0] = ldsb128<0>(pA);    a0A[1] = ldsb128<1024>(pA);
    a0A[2] = ldsb128<2048>(pA); a0A[3] = ldsb128<3072>(pA);
    a1A[0] = ldsb128<4096>(pA); a1A[1] = ldsb128<5120>(pA);
    a1A[2] = ldsb128<6144>(pA); a1A[3] = ldsb128<7168>(pA);
  }
  LGKM_0; SCHEDB;
  // entering kt=0: frags t0 in set A; DMA queue [t1(4), t2(4)]

#define TILE_BODY(NXTB, STGB, bC, a0C, a1C, bN, a0N, a1N, KOFF)               \
  {                                                                           \
    SCHEDB;                                                                   \
    VMC_4; /* tile k+1's DMA retired; k+2's stays in flight */                \
    BAR;   /* publish k+1; buf STGB's readers done two tiles ago */           \
    GLDS16(aS0 + (KOFF), &As[STGB][d0]);                                      \
    GLDS16(aS1 + (KOFF), &As[STGB][d1]);                                      \
    GLDS16(wS0 + (KOFF), &Bs[STGB][d0]);                                      \
    GLDS16(wS1 + (KOFF), &Bs[STGB][d1]);                                      \
    LGKM_0; SCHEDB; /* leftover prefetch reads (normally 0) - ~free */        \
    {                                                                         \
      lds_c8* pB = (lds_c8*)&Bs[NXTB][rdB];                                   \
      lds_c8* pA = (lds_c8*)&As[NXTB][rdA];                                   \
      __builtin_amdgcn_s_setprio(1);                                          \
      MFMA8I(a0C, bC + 0, 0, 0);                                              \
      __builtin_amdgcn_s_setprio(0);                                          \
      SCHEDB;                                                                 \
      bN[0] = ldsb128<0>(pB);    bN[1] = ldsb128<1024>(pB);                   \
      bN[2] = ldsb128<2048>(pB); bN[3] = ldsb128<3072>(pB);                   \
      SCHEDB;                                                                 \
      __builtin_amdgcn_s_setprio(1);                                          \
      MFMA8I(a0C, bC + 2, 0, 2);                                              \
      __builtin_amdgcn_s_setprio(0);                                          \
      SCHEDB;                                                                 \
      a0N[0] = ldsb128<0>(pA);    a0N[1] = ldsb128<1024>(pA);                 \
      a0N[2] = ldsb128<2048>(pA); a0N[3] = ldsb128<3072>(pA);                 \
      SCHEDB;                                                                 \
      __builtin_amdgcn_s_setprio(1);                                          \
      MFMA8I(a1C, bC + 0, 4, 0);                                              \
      __builtin_amdgcn_s_setprio(0);                                          \
      SCHEDB;                                                                 \
      a1N[0] = ldsb128<4096>(pA); a1N[1] = ldsb128<5120>(pA);                 \
      a1N[2] = ldsb128<6144>(pA); a1N[3] = ldsb128<7168>(pA);                 \
      SCHEDB;                                                                 \
      __builtin_amdgcn_s_setprio(1);                                          \
      MFMA8I(a1C, bC + 2, 4, 2);                                              \
      __builtin_amdgcn_s_setprio(0);                                          \
    }                                                                         \
    SCHEDB;                                                                   \
  }

  for (int kt = 0; kt < nk; kt += 4) {
    const long ko3 = (long)(kt + 3) * BKT;                        // < nk
    const long ko4 = (kt + 4 < nk) ? (long)(kt + 4) * BKT : 0;    // wrap ok
    const long ko5 = (kt + 5 < nk) ? (long)(kt + 5) * BKT : 0;
    const long ko6 = (kt + 6 < nk) ? (long)(kt + 6) * BKT : 0;
    TILE_BODY(1, 3, bA, a0A, a1A, bB, a0B, a1B, ko3);  // kt+0
    TILE_BODY(2, 0, bB, a0B, a1B, bA, a0A, a1A, ko4);  // kt+1
    TILE_BODY(3, 1, bA, a0A, a1A, bB, a0B, a1B, ko5);  // kt+2
    TILE_BODY(0, 2, bB, a0B, a1B, bA, a0A, a1A, ko6);  // kt+3
  }
#undef TILE_BODY

  // epilogue: C/D frag layout col=lane&15, row=(lane>>4)*4+v (dtype-indep)
  const long col0 = wRow0 + wn * 64 + (lane & 15);
  float scl[4], bs[4];
#pragma unroll
  for (int j = 0; j < 4; ++j) {
    scl[j] = scale[col0 + j * 16];
    bs[j] = bias[col0 + j * 16];
  }
  const long row0 = aRow0 + wm * 128 + ((lane >> 4) << 2);
#pragma unroll
  for (int i = 0; i < 8; ++i) {
#pragma unroll
    for (int v = 0; v < 4; ++v) {
      const float rs = s_a[row0 + i * 16 + v];
      float* cp = C + (row0 + i * 16 + v) * (long)N + col0;
#pragma unroll
      for (int j = 0; j < 4; ++j)
        cp[j * 16] = (float)acc[i][j][v] * (rs * scl[j]) + bs[j];
    }
  }
}

// correctness-only fallback (reads original fp32/int32 inputs)
__global__ void naive_w8a16(const float* __restrict__ inp,
                            const int* __restrict__ qw,
                            const float* __restrict__ scale,
                            const float* __restrict__ bias,
                            float* __restrict__ out, long M, long N, long K) {
  long idx = (long)blockIdx.x * blockDim.x + threadIdx.x;
  if (idx >= M * N) return;
  long col = idx % N, row = idx / N;
  const float* a = inp + row * K;
  const int* w = qw + col * K;
  float s = 0.f;
  for (long k = 0; k < K; k += 4) {
    float4 av = *reinterpret_cast<const float4*>(&a[k]);
    int4 wv = *reinterpret_cast<const int4*>(&w[k]);
    s += av.x * (float)wv.x + av.y * (float)wv.y + av.z * (float)wv.z +
         av.w * (float)wv.w;
  }
  out[idx] = s * scale[col] + bias[col];
}

extern "C" void kernel_launch(void* const* d_in, const int* in_sizes, int n_in,
                              void* d_out, int out_size, void* d_ws,
                              size_t ws_size, hipStream_t stream) {
  const float* inp = (const float*)d_in[0];   // [B,S,D_IN] f32
  const int* qw = (const int*)d_in[1];        // [D_OUT,D_IN] i32
  const float* scale = (const float*)d_in[2]; // [D_OUT]
  const float* bias = (const float*)d_in[3];  // [D_OUT]
  float* out = (float*)d_out;                 // [B,S,D_OUT] f32

  const long N = in_sizes[2];                 // 16384
  const long K = (long)in_sizes[1] / N;       // 4096
  const long M = (long)in_sizes[0] / K;       // 8192

  const size_t aB = (size_t)M * K;            // 32 MiB (i8)
  const size_t wB = (size_t)N * K;            // 64 MiB (i8)
  const size_t sB = (size_t)M * 4;            // row scales
  const long nk = K / BKT;

  if (ws_size >= aB + wB + sB && (M % BM) == 0 && (N % BN) == 0 &&
      K == 4096 && nk >= 8 && (nk % 4) == 0) {
    signed char* Ai8 = (signed char*)d_ws;
    signed char* Wi8 = (signed char*)d_ws + aB;
    float* sA = (float*)((char*)d_ws + aB + wB);
    quant_act<<<(int)M, 256, 0, stream>>>(inp, Ai8, sA, (int)K);
    pack_w<<<2048, 256, 0, stream>>>(qw, Wi8, N * K / 16);
    const int nwg = (int)((M / BM) * (N / BN));  // 2048
    gemm256_i8x<<<nwg, 512, 0, stream>>>(Ai8, Wi8, sA, scale, bias, out,
                                         (int)M, (int)N, (int)K);
  } else {
    long total = M * N;
    naive_w8a16<<<(int)((total + 255) / 256), 256, 0, stream>>>(
        inp, qw, scale, bias, out, M, N, K);
  }
}

// Round 16
// 694.028 us; speedup vs baseline: 1.1429x; 1.1429x over previous
//
#include <hip/hip_runtime.h>
#include <stdint.h>

typedef __attribute__((ext_vector_type(4))) int iv4;      // 4 VGPRs (16B)
typedef __attribute__((ext_vector_type(16))) char i8x16;

#define BM 256
#define BN 256
#define BKB 128   // K bytes per tile (i8); half-tile = [128 rows][128B] = 16KB

// ---- activation quantization: one block per row, per-row scale ----
__global__ __launch_bounds__(256) void quant_act(const float* __restrict__ in,
                                                 signed char* __restrict__ out,
                                                 float* __restrict__ s_a,
                                                 int K) {
  const int row = blockIdx.x;
  const int t = threadIdx.x;
  const float* a = in + (long)row * K;
  float4 v[4];
#pragma unroll
  for (int i = 0; i < 4; ++i)
    v[i] = reinterpret_cast<const float4*>(a)[t * 4 + i];
  float m = 0.f;
#pragma unroll
  for (int i = 0; i < 4; ++i) {
    m = fmaxf(m, fmaxf(fmaxf(fabsf(v[i].x), fabsf(v[i].y)),
                       fmaxf(fabsf(v[i].z), fabsf(v[i].w))));
  }
#pragma unroll
  for (int off = 32; off; off >>= 1) m = fmaxf(m, __shfl_xor(m, off));
  __shared__ float wmax[4];
  const int lane = t & 63, wvq = t >> 6;
  if (lane == 0) wmax[wvq] = m;
  __syncthreads();
  m = fmaxf(fmaxf(wmax[0], wmax[1]), fmaxf(wmax[2], wmax[3]));
  const float inv = m > 0.f ? 127.f / m : 0.f;
  if (t == 0) s_a[row] = m > 0.f ? m / 127.f : 0.f;
  i8x16 q;
#pragma unroll
  for (int i = 0; i < 4; ++i) {
    q[i * 4 + 0] = (char)(int)rintf(fminf(fmaxf(v[i].x * inv, -127.f), 127.f));
    q[i * 4 + 1] = (char)(int)rintf(fminf(fmaxf(v[i].y * inv, -127.f), 127.f));
    q[i * 4 + 2] = (char)(int)rintf(fminf(fmaxf(v[i].z * inv, -127.f), 127.f));
    q[i * 4 + 3] = (char)(int)rintf(fminf(fmaxf(v[i].w * inv, -127.f), 127.f));
  }
  reinterpret_cast<i8x16*>(out + (long)row * K)[t] = q;
}

// ---- weight pack: int32 (|v|<=127) -> int8 ----
__global__ void pack_w(const int* __restrict__ in, signed char* __restrict__ out,
                       long n16) {
  long stride = (long)gridDim.x * blockDim.x;
  for (long i = (long)blockIdx.x * blockDim.x + threadIdx.x; i < n16; i += stride) {
    i8x16 q;
#pragma unroll
    for (int c = 0; c < 4; ++c) {
      int4 w = reinterpret_cast<const int4*>(in)[i * 4 + c];
      q[c * 4 + 0] = (char)w.x;
      q[c * 4 + 1] = (char)w.y;
      q[c * 4 + 2] = (char)w.z;
      q[c * 4 + 3] = (char)w.w;
    }
    reinterpret_cast<i8x16*>(out)[i] = q;
  }
}

#define GLDS16(g, l)                                                          \
  __builtin_amdgcn_global_load_lds(                                           \
      (const __attribute__((address_space(1))) unsigned int*)(g),             \
      (__attribute__((address_space(3))) unsigned int*)(l), 16, 0, 0)

// Inline-asm ds_read_b128 (opaque to SIInsertWaitcnts; no clobbers in-loop
// so no hidden vmcnt(0) drains). rule #18: manual waits + sched_barrier(0).
typedef __attribute__((address_space(3))) const signed char lds_c8;

template <int OFF>
__device__ __forceinline__ iv4 ldsb128(lds_c8* p) {
  iv4 r;
  asm volatile("ds_read_b128 %0, %1 offset:%2" : "=v"(r) : "v"(p), "i"(OFF));
  return r;
}

#define BAR __builtin_amdgcn_s_barrier()
#define SCHEDB __builtin_amdgcn_sched_barrier(0)
#define LGKM_0 asm volatile("s_waitcnt lgkmcnt(0)")
#define LGKM_8 asm volatile("s_waitcnt lgkmcnt(8)")
#define VMC_4 asm volatile("s_waitcnt vmcnt(4)")

// 16 MFMAs for C-quadrant (I0, J0): sum over ks into same acc (K-recipe)
#define PH_MFMA(AF, BQ, I0, J0)                                               \
  _Pragma("unroll") for (int i = 0; i < 4; ++i)                               \
    _Pragma("unroll") for (int jj = 0; jj < 2; ++jj)                          \
      _Pragma("unroll") for (int ks = 0; ks < 2; ++ks)                        \
        acc[(I0) + i][(J0) + jj] = __builtin_amdgcn_mfma_i32_16x16x64_i8(     \
            AF[i][ks], BQ[jj][ks], acc[(I0) + i][(J0) + jj], 0, 0, 0)

// 256x256 int8 GEMM — faithful m201 8-phase choreography (i8 port):
// * half-tile = [128 rows][128B] (16KB); LDS [2 buf][2 half] x {A,B} = 128KB
// * 4 phases/K-tile = C-quadrant rotation (A0B0, A0B1, A1B1, A1B0);
//   per-phase reads 12/4/8/0 — each operand read ONCE per tile
// * reads issue PRE-barrier, lgkmcnt(0) POST-barrier (latency hides under
//   barrier arrival); 16 MFMA per phase wrapped in setprio
// * staging ~1.75 tiles deep: each phase stages 1 half-tile (2 gload_lds);
//   slots: ph1->A1(t+1), ph2->B0(t+1), ph3->B1(t+2), ph4->A0(t+2); each
//   target half's last ds_read was lgkm-drained >=1 barrier before overwrite
// * ONE vmcnt(4) per K-tile (pre ph4-barrier): in-order retirement covers
//   ALL of tile t+1 (issued 4-7 phases ago -> free); 2 halves stay in flight
// * 8-slot/row XOR swizzle: phys slot = logical ^ ((row>>1)&7); write side
//   inverse-permutes the global source column; reads land 2 lanes/bank (free)
__global__ __launch_bounds__(512, 2) void gemm256_m2(
    const signed char* __restrict__ A,   // [M][K] i8 (row-quantized)
    const signed char* __restrict__ W,   // [N][K] i8
    const float* __restrict__ s_a,       // [M] activation row scales
    const float* __restrict__ scale,     // [N] weight col scales
    const float* __restrict__ bias,      // [N]
    float* __restrict__ C,               // [M][N] f32
    int M, int N, int K) {
  __shared__ __align__(16) signed char As[2][2][128 * 128];  // 64 KiB
  __shared__ __align__(16) signed char Bs[2][2][128 * 128];  // 64 KiB

  const int tid = threadIdx.x;
  const int lane = tid & 63;
  const int wv = tid >> 6;       // 0..7
  const int wm = wv >> 2;        // 0..1  (wave rows: half wm)
  const int wn = wv & 3;         // 0..3  (wave cols: 64 within B-half wn>>1)

  const int nwg = gridDim.x;
  const int bid = blockIdx.x;
  const int wg = ((nwg & 7) == 0) ? ((bid & 7) * (nwg >> 3) + (bid >> 3)) : bid;
  const int mT = M / BM;
  const int bm = wg % mT;        // M-fast: neighbors share W panel
  const int bn = wg / mT;

  const long aRow0 = (long)bm * BM;
  const long wRow0 = (long)bn * BN;

  // ---- staging: issue q in {0,1}; wave wv covers 1KB per issue.
  // lane l -> linear LDS slot (l&7) at row (q*8+wv)*8+(l>>3); it must carry
  // logical slot (l&7)^((row>>1)&7) = (l&7)^(((wv&1)<<2)|(l>>4)).
  const int sRow0 = (0 * 8 + wv) * 8 + (lane >> 3);
  const int sRow1 = (1 * 8 + wv) * 8 + (lane >> 3);
  const int srcslot = (lane & 7) ^ (((wv & 1) << 2) | (lane >> 4));
  const signed char* aS0 = A + (aRow0 + sRow0) * (long)K + srcslot * 16;
  const signed char* aS1 = A + (aRow0 + sRow1) * (long)K + srcslot * 16;
  const signed char* wS0 = W + (wRow0 + sRow0) * (long)K + srcslot * 16;
  const signed char* wS1 = W + (wRow0 + sRow1) * (long)K + srcslot * 16;
  const long AH = 128 * (long)K;           // second-half source row offset
  const int d0 = (0 * 8 + wv) * 1024 + lane * 16;
  const int d1 = (1 * 8 + wv) * 1024 + lane * 16;

  // ---- read base: row (l&15), phys slot ((l>>4)^((l>>1)&7)); ks1 = ^64.
  const int rdLane = (lane & 15) * 128 + (((lane >> 4) ^ ((lane >> 1) & 7)) * 16);
  const int rdB_off = (wn & 1) * 8192;     // wave's 64 B-rows within its half

  iv4 acc[8][4] = {};
  iv4 aF[4][2], bQ0[2][2], bQ1[2][2];

  const int nk = K / BKB;   // 32

  // ---- prologue: t0 all 4 halves -> buf0; t1.B1, t1.A0 -> buf1
  GLDS16(aS0, &As[0][0][d0]);           GLDS16(aS1, &As[0][0][d1]);
  GLDS16(aS0 + AH, &As[0][1][d0]);      GLDS16(aS1 + AH, &As[0][1][d1]);
  GLDS16(wS0, &Bs[0][0][d0]);           GLDS16(wS1, &Bs[0][0][d1]);
  GLDS16(wS0 + AH, &Bs[0][1][d0]);      GLDS16(wS1 + AH, &Bs[0][1][d1]);
  GLDS16(wS0 + AH + BKB, &Bs[1][1][d0]); GLDS16(wS1 + AH + BKB, &Bs[1][1][d1]);
  GLDS16(aS0 + BKB, &As[1][0][d0]);     GLDS16(aS1 + BKB, &As[1][0][d1]);
  VMC_4;   // 12 issued -> retire 8 oldest = all of t0; t1.{B1,A0} in flight
  BAR;

#define TILE_BODY(CUR, NXT, KO1, KO2)                                         \
  {                                                                           \
    lds_c8* pAk0 = (lds_c8*)&As[CUR][wm][rdLane];                             \
    lds_c8* pAk1 = (lds_c8*)&As[CUR][wm][rdLane ^ 64];                        \
    lds_c8* pBk0 = (lds_c8*)&Bs[CUR][wn >> 1][rdB_off + rdLane];              \
    lds_c8* pBk1 = (lds_c8*)&Bs[CUR][wn >> 1][rdB_off + (rdLane ^ 64)];       \
    /* ph1 (A0,B0): 12 reads; stage A1(t+1) */                                \
    bQ0[0][0] = ldsb128<0>(pBk0);    bQ0[0][1] = ldsb128<0>(pBk1);            \
    bQ0[1][0] = ldsb128<2048>(pBk0); bQ0[1][1] = ldsb128<2048>(pBk1);         \
    aF[0][0] = ldsb128<0>(pAk0);     aF[0][1] = ldsb128<0>(pAk1);             \
    aF[1][0] = ldsb128<2048>(pAk0);  aF[1][1] = ldsb128<2048>(pAk1);          \
    aF[2][0] = ldsb128<4096>(pAk0);  aF[2][1] = ldsb128<4096>(pAk1);          \
    aF[3][0] = ldsb128<6144>(pAk0);  aF[3][1] = ldsb128<6144>(pAk1);          \
    GLDS16(aS0 + AH + (KO1), &As[NXT][1][d0]);                                \
    GLDS16(aS1 + AH + (KO1), &As[NXT][1][d1]);                                \
    LGKM_8; SCHEDB;                                                           \
    BAR;                                                                      \
    LGKM_0; SCHEDB;                                                           \
    __builtin_amdgcn_s_setprio(1);                                            \
    PH_MFMA(aF, bQ0, 0, 0);                                                   \
    __builtin_amdgcn_s_setprio(0);                                            \
    SCHEDB; BAR;                                                              \
    /* ph2 (A0,B1): 4 reads; stage B0(t+1) */                                 \
    bQ1[0][0] = ldsb128<4096>(pBk0); bQ1[0][1] = ldsb128<4096>(pBk1);         \
    bQ1[1][0] = ldsb128<6144>(pBk0); bQ1[1][1] = ldsb128<6144>(pBk1);         \
    GLDS16(wS0 + (KO1), &Bs[NXT][0][d0]);                                     \
    GLDS16(wS1 + (KO1), &Bs[NXT][0][d1]);                                     \
    BAR;                                                                      \
    LGKM_0; SCHEDB;                                                           \
    __builtin_amdgcn_s_setprio(1);                                            \
    PH_MFMA(aF, bQ1, 0, 2);                                                   \
    __builtin_amdgcn_s_setprio(0);                                            \
    SCHEDB; BAR;                                                              \
    /* ph3 (A1,B1): 8 reads; stage B1(t+2) */                                 \
    aF[0][0] = ldsb128<8192>(pAk0);  aF[0][1] = ldsb128<8192>(pAk1);          \
    aF[1][0] = ldsb128<10240>(pAk0); aF[1][1] = ldsb128<10240>(pAk1);         \
    aF[2][0] = ldsb128<12288>(pAk0); aF[2][1] = ldsb128<12288>(pAk1);         \
    aF[3][0] = ldsb128<14336>(pAk0); aF[3][1] = ldsb128<14336>(pAk1);         \
    GLDS16(wS0 + AH + (KO2), &Bs[CUR][1][d0]);                                \
    GLDS16(wS1 + AH + (KO2), &Bs[CUR][1][d1]);                                \
    BAR;                                                                      \
    LGKM_0; SCHEDB;                                                           \
    __builtin_amdgcn_s_setprio(1);                                            \
    PH_MFMA(aF, bQ1, 4, 2);                                                   \
    __builtin_amdgcn_s_setprio(0);                                            \
    SCHEDB; BAR;                                                              \
    /* ph4 (A1,B0): 0 reads; stage A0(t+2); vmcnt(4) publishes all of t+1 */  \
    GLDS16(aS0 + (KO2), &As[CUR][0][d0]);                                     \
    GLDS16(aS1 + (KO2), &As[CUR][0][d1]);                                     \
    __builtin_amdgcn_s_setprio(1);                                            \
    PH_MFMA(aF, bQ0, 4, 0);                                                   \
    __builtin_amdgcn_s_setprio(0);                                            \
    VMC_4; SCHEDB;                                                            \
    BAR;                                                                      \
  }

  for (int kt = 0; kt < nk; kt += 2) {
    const long ka1 = (long)(kt + 1) * BKB;                        // < nk
    const long ka2 = (kt + 2 < nk) ? (long)(kt + 2) * BKB : 0;    // wrap ok
    const long kb1 = ka2;
    const long kb2 = (kt + 3 < nk) ? (long)(kt + 3) * BKB : 0;
    TILE_BODY(0, 1, ka1, ka2);
    TILE_BODY(1, 0, kb1, kb2);
  }
#undef TILE_BODY

  // epilogue: C/D frag layout col=lane&15, row=(lane>>4)*4+v (dtype-indep)
  const long col0 = wRow0 + wn * 64 + (lane & 15);
  float scl[4], bs[4];
#pragma unroll
  for (int j = 0; j < 4; ++j) {
    scl[j] = scale[col0 + j * 16];
    bs[j] = bias[col0 + j * 16];
  }
  const long row0 = aRow0 + wm * 128 + ((lane >> 4) << 2);
#pragma unroll
  for (int i = 0; i < 8; ++i) {
#pragma unroll
    for (int v = 0; v < 4; ++v) {
      const float rs = s_a[row0 + i * 16 + v];
      float* cp = C + (row0 + i * 16 + v) * (long)N + col0;
#pragma unroll
      for (int j = 0; j < 4; ++j)
        cp[j * 16] = (float)acc[i][j][v] * (rs * scl[j]) + bs[j];
    }
  }
}

// correctness-only fallback (reads original fp32/int32 inputs)
__global__ void naive_w8a16(const float* __restrict__ inp,
                            const int* __restrict__ qw,
                            const float* __restrict__ scale,
                            const float* __restrict__ bias,
                            float* __restrict__ out, long M, long N, long K) {
  long idx = (long)blockIdx.x * blockDim.x + threadIdx.x;
  if (idx >= M * N) return;
  long col = idx % N, row = idx / N;
  const float* a = inp + row * K;
  const int* w = qw + col * K;
  float s = 0.f;
  for (long k = 0; k < K; k += 4) {
    float4 av = *reinterpret_cast<const float4*>(&a[k]);
    int4 wv = *reinterpret_cast<const int4*>(&w[k]);
    s += av.x * (float)wv.x + av.y * (float)wv.y + av.z * (float)wv.z +
         av.w * (float)wv.w;
  }
  out[idx] = s * scale[col] + bias[col];
}

extern "C" void kernel_launch(void* const* d_in, const int* in_sizes, int n_in,
                              void* d_out, int out_size, void* d_ws,
                              size_t ws_size, hipStream_t stream) {
  const float* inp = (const float*)d_in[0];   // [B,S,D_IN] f32
  const int* qw = (const int*)d_in[1];        // [D_OUT,D_IN] i32
  const float* scale = (const float*)d_in[2]; // [D_OUT]
  const float* bias = (const float*)d_in[3];  // [D_OUT]
  float* out = (float*)d_out;                 // [B,S,D_OUT] f32

  const long N = in_sizes[2];                 // 16384
  const long K = (long)in_sizes[1] / N;       // 4096
  const long M = (long)in_sizes[0] / K;       // 8192

  const size_t aB = (size_t)M * K;            // 32 MiB (i8)
  const size_t wB = (size_t)N * K;            // 64 MiB (i8)
  const size_t sB = (size_t)M * 4;            // row scales
  const long nk = K / BKB;

  if (ws_size >= aB + wB + sB && (M % BM) == 0 && (N % BN) == 0 &&
      K == 4096 && nk >= 4 && (nk % 2) == 0) {
    signed char* Ai8 = (signed char*)d_ws;
    signed char* Wi8 = (signed char*)d_ws + aB;
    float* sA = (float*)((char*)d_ws + aB + wB);
    quant_act<<<(int)M, 256, 0, stream>>>(inp, Ai8, sA, (int)K);
    pack_w<<<2048, 256, 0, stream>>>(qw, Wi8, N * K / 16);
    const int nwg = (int)((M / BM) * (N / BN));  // 2048
    gemm256_m2<<<nwg, 512, 0, stream>>>(Ai8, Wi8, sA, scale, bias, out,
                                        (int)M, (int)N, (int)K);
  } else {
    long total = M * N;
    naive_w8a16<<<(int)((total + 255) / 256), 256, 0, stream>>>(
        inp, qw, scale, bias, out, M, N, K);
  }
}